// Round 1
// baseline (990.960 us; speedup 1.0000x reference)
//
#include <hip/hip_runtime.h>

// Masked mean-pool: out[b,d] = sum_s embed[b,s,d]*mask[b,s] / sum_s mask[b,s]
// mask[b,s] = token_ids[b,s] not in {0 (PAD), 101 (CLS), 102 (SEP)}
//
// B=512, S=512, D=768, fp32. Streaming-read bound: ~805 MB embed.
// Roofline @6.3 TB/s achievable: ~128 us.
//
// V2 change: the grid is pinned at B=512 blocks (2 blocks/CU). The previous
// version used 192 threads/block -> 6 waves/CU (1.5/SIMD) -> latency-starved
// at 13% of HBM BW. Split S 4-ways inside the block: 768 threads (12 waves)
// -> 24 waves/CU (6/SIMD), partial sums reduced through LDS.

constexpr int B  = 512;
constexpr int S  = 512;
constexpr int D  = 768;
constexpr int NV = D / 4;     // 192 float4 columns
constexpr int CH = 4;         // S-chunks per block
constexpr int SCH = S / CH;   // 128 rows per chunk
constexpr int NT = NV * CH;   // 768 threads = 12 waves

__global__ __launch_bounds__(NT) void masked_mean_kernel(
    const float4* __restrict__ embed,   // [B, S, NV] as float4
    const int* __restrict__ tok,        // [B, S]
    float4* __restrict__ out)           // [B, NV]
{
    const int b = blockIdx.x;
    const int t = threadIdx.x;

    // Wave-aligned decomposition: wave w (0..11) -> chunk w/3, col base (w%3)*64.
    // Each wave's 64 lanes read 64 consecutive float4 = 1 KB coalesced.
    const int w    = t >> 6;
    const int lane = t & 63;
    const int col  = (w % 3) * 64 + lane;
    const int ch   = w / 3;

    __shared__ float  maskf[S];         // 2 KB
    __shared__ float4 accs[CH][NV];     // 12 KB
    __shared__ float  cnts[CH];

    // Stage mask for this batch row (coalesced int loads, threads 0..511).
    if (t < S) {
        const int id = tok[b * S + t];
        maskf[t] = (id != 0 && id != 101 && id != 102) ? 1.0f : 0.0f;
    }
    __syncthreads();

    // Stream this chunk's rows. maskf[s] is a same-address LDS broadcast per
    // wave, so every lane redundantly accumulates cnt -> no cross-lane reduce.
    const int s0 = ch * SCH;
    const float4* row = embed + (size_t)b * S * NV + (size_t)s0 * NV + col;
    float4 acc = make_float4(0.f, 0.f, 0.f, 0.f);
    float cnt = 0.f;

#pragma unroll 8
    for (int s = 0; s < SCH; ++s) {
        const float  m = maskf[s0 + s];
        const float4 v = row[(size_t)s * NV];
        cnt += m;
        acc.x = fmaf(v.x, m, acc.x);
        acc.y = fmaf(v.y, m, acc.y);
        acc.z = fmaf(v.z, m, acc.z);
        acc.w = fmaf(v.w, m, acc.w);
    }

    accs[ch][col] = acc;
    if (col == 0) cnts[ch] = cnt;
    __syncthreads();

    // Final reduce over chunks: threads 0..191, contiguous float4 LDS reads.
    if (t < NV) {
        float4 a = accs[0][t];
#pragma unroll
        for (int k = 1; k < CH; ++k) {
            const float4 p = accs[k][t];
            a.x += p.x; a.y += p.y; a.z += p.z; a.w += p.w;
        }
        const float c = cnts[0] + cnts[1] + cnts[2] + cnts[3];
        const float inv = 1.0f / c;
        out[b * NV + t] = make_float4(a.x * inv, a.y * inv, a.z * inv, a.w * inv);
    }
}

extern "C" void kernel_launch(void* const* d_in, const int* in_sizes, int n_in,
                              void* d_out, int out_size, void* d_ws, size_t ws_size,
                              hipStream_t stream) {
    const float4* embed = (const float4*)d_in[0];
    const int* tok = (const int*)d_in[1];
    float4* out = (float4*)d_out;

    masked_mean_kernel<<<dim3(B), dim3(NT), 0, stream>>>(embed, tok, out);
}